// Round 3
// baseline (2974.482 us; speedup 1.0000x reference)
//
#include <hip/hip_runtime.h>
#include <hip/hip_bf16.h>
#include <cstdint>
#include <cstddef>

// Problem constants
#define H_    128
#define IN_   86
#define OUT_  66
#define T_    50
#define B_    8192
#define NPOSE 15

// Round-8 design: unlock regalloc + software-pipelined weight loads.
//  - Post-mortem r6/r7: barrier-count fusion was NEUTRAL (1642 vs 1810);
//    VGPR pinned at 64 in all rounds -> compiler targets 8 waves/SIMD
//    occupancy we never launch, so B-frag loads (60 x 1KB/wave/step, L2/LLC
//    latency) are never pipelined -> ~90% stall -> chip likely downclocks.
//  - Fix 1: amdgpu_waves_per_eu(4,4) (exactly 4 waves/SIMD) -> 128-VGPR
//    budget for the scheduler.
//  - Fix 2: gemm_pipe: fully-unrolled k-loop, static 2-deep double buffer
//    (B-frags x4 + A hi/lo) -> loads of k+1 overlap MFMAs of k. Liveness is
//    intra-phase only (no cross-barrier state beyond accs -> no r6 spills).
//  - Fix 3: back to BR=16 / 512 thr / grid 512 (2 blocks/CU) for cross-block
//    overlap (r7 showed 1 block/CU costs ~10%).
//  - Fusion kept: gates1(t) + gates0(t+1) in one fat GEMM phase; main loop
//    = 2 barriers/timestep. Accumulation order unchanged -> bit-identical.
// K0 = 224: [u(86)|pad(10)|h1(128)] ; K1 = 256: [h1|h2]
#define K0T 7
#define K1T 8
#define KDT 4
#define NT0 32
#define NT1 32
#define NTD 5
#define S0  232   // A0 row stride (ushorts); 116 dwords = 4*odd (2-way, free)
#define S1  264   // A1 row stride; 132 dwords = 4*odd
#define BR  16
#define THR 512

// ws layout (bytes) — hi-only packed B fragments
#define B0P_OFF 0
#define B0P_SZ  (K0T * NT0 * 1024)       // 229376
#define B1P_OFF (B0P_OFF + B0P_SZ)
#define B1P_SZ  (K1T * NT1 * 1024)       // 262144
#define BDP_OFF (B1P_OFF + B1P_SZ)       // 491520
#define BDP_SZ  (KDT * NTD * 1024)       // 20480
#define B0P_N (B0P_SZ / 2)               // 114688
#define B1P_N (B1P_SZ / 2)               // 131072
#define TOT_N ((B0P_SZ + B1P_SZ + BDP_SZ) / 2)   // 256000

typedef __attribute__((ext_vector_type(8))) short bfrag;
typedef __attribute__((ext_vector_type(4))) float ffrag;

#define MFMA(AC, AA, BB) \
  AC = __builtin_amdgcn_mfma_f32_16x16x32_bf16((AA), (BB), (AC), 0, 0, 0)

__device__ __forceinline__ unsigned short bf16rn(float f) {
  union { float f; unsigned int u; } cv; cv.f = f;
  unsigned int u = cv.u;
  u += 0x7FFFu + ((u >> 16) & 1u);   // round-to-nearest-even
  return (unsigned short)(u >> 16);
}
__device__ __forceinline__ float bf16tof(unsigned short h) {
  union { unsigned int u; float f; } cv; cv.u = ((unsigned int)h) << 16;
  return cv.f;
}
__device__ __forceinline__ float sigmoid_f(float v) {
  return __fdividef(1.f, 1.f + __expf(-v));
}
__device__ __forceinline__ float tanh_f(float v) {
  float av = fabsf(v);
  float e  = __expf(-2.f * av);
  float t  = __fdividef(1.f - e, 1.f + e);
  return copysignf(t, v);
}

// ---------------- prep: pack hi-only weights in MFMA fragment order ---------
__global__ void wm_prep(
    const float* __restrict__ Wih0, const float* __restrict__ Whh0,
    const float* __restrict__ Wih1, const float* __restrict__ Whh1,
    const float* __restrict__ Wd,
    unsigned short* __restrict__ wsu)
{
  const int idx = blockIdx.x * 256 + threadIdx.x;
  if (idx >= TOT_N) return;
  int region, l;
  if (idx < B0P_N)               { region = 0; l = idx; }
  else if (idx < B0P_N + B1P_N)  { region = 1; l = idx - B0P_N; }
  else                           { region = 2; l = idx - (B0P_N + B1P_N); }

  int k, nt, lane, j;
  if (region < 2) {
    k  = l >> 14;            // 32 tiles * 512 ushorts = 16384 per ktile
    int r1 = l & 16383;
    nt = r1 >> 9;
    int li = r1 & 511;
    lane = li >> 3; j = li & 7;
  } else {
    k  = l / 2560;           // 5 * 512 per ktile
    int r1 = l % 2560;
    nt = r1 >> 9;
    int li = r1 & 511;
    lane = li >> 3; j = li & 7;
  }
  const int n  = nt * 16 + (lane & 15);
  const int kk = k * 32 + (lane >> 4) * 8 + j;

  float v = 0.f;
  if (region == 0) {
    if (kk < IN_)                    v = Wih0[n * IN_ + kk];
    else if (kk >= 96 && kk < 224)   v = Whh0[n * H_ + (kk - 96)];
  } else if (region == 1) {
    v = (kk < H_) ? Wih1[n * H_ + kk] : Whh1[n * H_ + (kk - H_)];
  } else {
    if (n < OUT_)                    v = Wd[n * H_ + kk];
  }
  wsu[idx] = bf16rn(v);
}

// ---------------- GEMM helper: software-pipelined K segment [KF, KL) --------
// Fully unrolled; static 2-deep double buffer so loads of tile k+1 are in
// flight while MFMAs of tile k issue. All buffer indices are compile-time
// constants after unroll (no scratch).
template<int KF, int KL>
__device__ __forceinline__ void gemm_pipe(const unsigned short* Ah, const unsigned short* Al,
                                          int ab, const char* __restrict__ Bb, int NT,
                                          int uw, int lane16, ffrag acc[4]) {
  bfrag bb[2][4];
  bfrag ah[2], al[2];
  #pragma unroll
  for (int g = 0; g < 4; ++g)
    bb[0][g] = *(const bfrag*)(Bb + (size_t)(KF * NT + g * 8 + uw) * 1024 + lane16);
  ah[0] = *(const bfrag*)(Ah + ab + KF * 32);
  al[0] = *(const bfrag*)(Al + ab + KF * 32);
  #pragma unroll
  for (int k = KF; k < KL; ++k) {
    const int cur = (k - KF) & 1;
    const int nxt = cur ^ 1;
    if (k + 1 < KL) {
      #pragma unroll
      for (int g = 0; g < 4; ++g)
        bb[nxt][g] = *(const bfrag*)(Bb + (size_t)((k + 1) * NT + g * 8 + uw) * 1024 + lane16);
      ah[nxt] = *(const bfrag*)(Ah + ab + (k + 1) * 32);
      al[nxt] = *(const bfrag*)(Al + ab + (k + 1) * 32);
    }
    #pragma unroll
    for (int g = 0; g < 4; ++g) MFMA(acc[g], ah[cur], bb[cur][g]);
    #pragma unroll
    for (int g = 0; g < 4; ++g) MFMA(acc[g], al[cur], bb[cur][g]);
  }
}

// ---------------- main persistent-recurrence kernel --------------------------
__global__ __attribute__((amdgpu_flat_work_group_size(THR, THR),
                          amdgpu_waves_per_eu(4, 4)))
void wm_main(
    const float* __restrict__ x,
    const char*  __restrict__ wsb,
    const float* __restrict__ bih0, const float* __restrict__ bhh0,
    const float* __restrict__ bih1, const float* __restrict__ bhh1,
    const float* __restrict__ bd,
    float* __restrict__ out)
{
  __shared__ __align__(16) unsigned short A0h[BR * S0];
  __shared__ __align__(16) unsigned short A0l[BR * S0];
  __shared__ __align__(16) unsigned short A1h[BR * S1];
  __shared__ __align__(16) unsigned short A1l[BR * S1];

  const int tid  = threadIdx.x;
  const int lane = tid & 63;
  const int uw   = tid >> 6;      // wave id = unit-slice id (0..7)
  const int ln15 = lane & 15;
  const int quad = lane >> 4;
  const int lane16 = lane * 16;

  const char* B0 = wsb + B0P_OFF;
  const char* B1 = wsb + B1P_OFF;
  const char* BD = wsb + BDP_OFF;

  // zero LDS (h/c zero-init; A0 pads [86,96) and [224,232) stay zero)
  for (int i = tid; i < BR * S0; i += THR) { A0h[i] = 0; A0l[i] = 0; }
  for (int i = tid; i < BR * S1; i += THR) { A1h[i] = 0; A1l[i] = 0; }

  // bias preload — this wave's unit col = uw*16 + ln15, per gate g
  float b0r[4], b1r[4];
  #pragma unroll
  for (int g = 0; g < 4; ++g) {
    const int n = g * 128 + uw * 16 + ln15;
    b0r[g] = bih0[n] + bhh0[n];
    b1r[g] = bih1[n] + bhh1[n];
  }
  // dense head: waves 0..4 own o-tile uw (o = uw*16 + ln15)
  const int od = uw * 16 + ln15;
  const float bdr = (uw < NTD && od < OUT_) ? bd[od] : 0.f;

  float c1[4], c2[4];
  #pragma unroll
  for (int r = 0; r < 4; ++r) { c1[r] = 0.f; c2[r] = 0.f; }

  const int a0b  = ln15 * S0 + quad * 8;   // A-frag offset (row ln15)
  const int a1b  = ln15 * S1 + quad * 8;
  const int prow = quad * 4;               // C/D rows = prow + r
  const int unit = uw * 16 + ln15;         // this lane's unit column
  const int xr_row = tid >> 5;             // staging: 16 rows x 32 lanes
  const int xr_col = tid & 31;

  // pointwise lambdas ---------------------------------------------------------
  auto pw_l1 = [&](const ffrag a4[4]) {    // h1 from acc0; writes A0[96+], A1[0+]
    #pragma unroll
    for (int rr = 0; rr < 4; ++rr) {
      const float ig = sigmoid_f(a4[0][rr]);
      const float fg = sigmoid_f(a4[1][rr]);
      const float gg = tanh_f(a4[2][rr]);
      const float og = sigmoid_f(a4[3][rr]);
      const float c  = fmaf(fg, c1[rr], ig * gg);
      c1[rr] = c;
      const float h  = og * tanh_f(c);
      const unsigned short hi = bf16rn(h);
      const unsigned short lo = bf16rn(h - bf16tof(hi));
      const int row = prow + rr;
      A0h[row * S0 + 96 + unit] = hi;  A0l[row * S0 + 96 + unit] = lo;
      A1h[row * S1 + unit]      = hi;  A1l[row * S1 + unit]      = lo;
    }
  };
  auto pw_l2 = [&](const ffrag a4[4]) {    // h2 from acc1; writes A1[128+]
    #pragma unroll
    for (int rr = 0; rr < 4; ++rr) {
      const float ig = sigmoid_f(a4[0][rr]);
      const float fg = sigmoid_f(a4[1][rr]);
      const float gg = tanh_f(a4[2][rr]);
      const float og = sigmoid_f(a4[3][rr]);
      const float c  = fmaf(fg, c2[rr], ig * gg);
      c2[rr] = c;
      const float h  = og * tanh_f(c);
      const unsigned short hi = bf16rn(h);
      const unsigned short lo = bf16rn(h - bf16tof(hi));
      const int row = prow + rr;
      A1h[row * S1 + 128 + unit] = hi;  A1l[row * S1 + 128 + unit] = lo;
    }
  };
  auto binit = [&](ffrag a4[4], const float bv[4]) {
    #pragma unroll
    for (int g = 0; g < 4; ++g) a4[g] = (ffrag){bv[g], bv[g], bv[g], bv[g]};
  };
  auto stage_write = [&](float v, int idx) {
    const unsigned short hi = bf16rn(v);
    A0h[idx] = hi;
    A0l[idx] = bf16rn(v - bf16tof(hi));
  };

  __syncthreads();   // zero-fill visible before staging overwrites

  // ---- prologue: stage x(0), compute acc0(0) --------------------------------
  {
    const float* xr = x + ((size_t)(blockIdx.x * BR + xr_row) * T_ + 0) * IN_;
    const float v0 = xr[xr_col];
    const float v1 = xr[xr_col + 32];
    float v2 = 0.f;
    if (xr_col < IN_ - 64) v2 = xr[xr_col + 64];
    stage_write(v0, xr_row * S0 + xr_col);
    stage_write(v1, xr_row * S0 + xr_col + 32);
    if (xr_col < IN_ - 64) stage_write(v2, xr_row * S0 + xr_col + 64);
  }
  __syncthreads();

  ffrag acc0[4], acc1[4];
  binit(acc0, b0r);
  gemm_pipe<0, K0T>(A0h, A0l, a0b, B0, NT0, uw, lane16, acc0);
  __syncthreads();

  // ---- fused main loop: t = 0..49 (2 barriers per timestep) -----------------
  for (int t = 0; t < T_; ++t) {
    // W phase: x loads issued early, pointwise, LDS writes.
    float v0 = 0.f, v1 = 0.f, v2 = 0.f;
    const bool stg = (t < T_ - 1);         // t=49: u(50)=x(49), already staged
    if (stg) {
      const float* xr = x + ((size_t)(blockIdx.x * BR + xr_row) * T_ + (t + 1)) * IN_;
      v0 = xr[xr_col];
      v1 = xr[xr_col + 32];
      if (xr_col < IN_ - 64) v2 = xr[xr_col + 64];
    }
    if (t > 0) pw_l2(acc1);                // h2(t-1)
    pw_l1(acc0);                           // h1(t)
    if (stg) {
      stage_write(v0, xr_row * S0 + xr_col);
      stage_write(v1, xr_row * S0 + xr_col + 32);
      if (xr_col < IN_ - 64) stage_write(v2, xr_row * S0 + xr_col + 64);
    }
    __syncthreads();   // h1(t), h2(t-1), x(t+1) visible

    // G phase: gates1(t) + gates0(t+1) — independent, one fat phase.
    binit(acc1, b1r);
    gemm_pipe<0, K1T>(A1h, A1l, a1b, B1, NT1, uw, lane16, acc1);
    binit(acc0, b0r);
    gemm_pipe<0, K0T>(A0h, A0l, a0b, B0, NT0, uw, lane16, acc0);
    __syncthreads();   // all reads done before next W overwrites
  }

  // ---- tail: t = 50..64 (pose feedback breaks full fusion) ------------------
  for (int t = T_; t < T_ + NPOSE; ++t) {
    const bool more = (t < T_ + NPOSE - 1);
    // Wa: h1(t) (+ h2(49) once)
    if (t == T_) pw_l2(acc1);              // h2(49)
    pw_l1(acc0);                           // h1(t)
    __syncthreads();

    // Ga: gates1(t) full + gates0(t+1) k-tiles 3..6 (h1-dependent part)
    binit(acc1, b1r);
    gemm_pipe<0, K1T>(A1h, A1l, a1b, B1, NT1, uw, lane16, acc1);
    if (more) {
      binit(acc0, b0r);
      gemm_pipe<3, K0T>(A0h, A0l, a0b, B0, NT0, uw, lane16, acc0);
    }
    __syncthreads();

    // Wb: h2(t)
    pw_l2(acc1);
    __syncthreads();

    // Gb: dense head (waves 0..4)
    const int s = t - T_;
    if (uw < NTD) {
      ffrag dacc = (ffrag){bdr, bdr, bdr, bdr};
      #pragma unroll
      for (int k = 0; k < KDT; ++k) {
        const bfrag ah = *(const bfrag*)(A1h + a1b + 128 + k * 32);
        const bfrag al = *(const bfrag*)(A1l + a1b + 128 + k * 32);
        const bfrag bh = *(const bfrag*)(BD + (size_t)(k * NTD + uw) * 1024 + lane16);
        MFMA(dacc, ah, bh);
        MFMA(dacc, al, bh);
      }
      if (od < OUT_) {
        #pragma unroll
        for (int rr = 0; rr < 4; ++rr) {
          const int row = prow + rr;
          const float v = dacc[rr];
          out[((size_t)(blockIdx.x * BR + row) * NPOSE + s) * OUT_ + od] = v;
          if (s < NPOSE - 1) {
            const unsigned short hi = bf16rn(v);
            A0h[row * S0 + od] = hi;
            A0l[row * S0 + od] = bf16rn(v - bf16tof(hi));
          }
        }
      }
    }
    __syncthreads();   // pose visible

    // Gc: gates0(t+1) k-tiles 0..2 (pose|cond region). Reads A0[0..96) only;
    // next Wa writes A0[96+]/A1 — disjoint, no barrier needed here.
    if (more) {
      gemm_pipe<0, 3>(A0h, A0l, a0b, B0, NT0, uw, lane16, acc0);
    }
  }
}

extern "C" void kernel_launch(void* const* d_in, const int* in_sizes, int n_in,
                              void* d_out, int out_size, void* d_ws, size_t ws_size,
                              hipStream_t stream)
{
  const float* x    = (const float*)d_in[0];
  const float* Wih0 = (const float*)d_in[1];
  const float* Whh0 = (const float*)d_in[2];
  const float* bih0 = (const float*)d_in[3];
  const float* bhh0 = (const float*)d_in[4];
  const float* Wih1 = (const float*)d_in[5];
  const float* Whh1 = (const float*)d_in[6];
  const float* bih1 = (const float*)d_in[7];
  const float* bhh1 = (const float*)d_in[8];
  const float* Wd   = (const float*)d_in[9];
  const float* bd   = (const float*)d_in[10];

  wm_prep<<<(TOT_N + 255) / 256, 256, 0, stream>>>(Wih0, Whh0, Wih1, Whh1, Wd,
                                                   (unsigned short*)d_ws);
  wm_main<<<B_ / BR, THR, 0, stream>>>(x, (const char*)d_ws,
                                       bih0, bhh0, bih1, bhh1, bd,
                                       (float*)d_out);
}

// Round 4
// 1694.042 us; speedup vs baseline: 1.7558x; 1.7558x over previous
//
#include <hip/hip_runtime.h>
#include <hip/hip_bf16.h>
#include <cstdint>
#include <cstddef>

// Problem constants
#define H_    128
#define IN_   86
#define OUT_  66
#define T_    50
#define B_    8192
#define NPOSE 15

// Round-9 design: L1-bandwidth attack.
//  Post-mortem r0-r3: kernel is L1-return-BW bound on weight streaming
//  (983KB/CU/step @ ~64B/cyc ~= 15.4K cyc ~= measured step wall at the
//  observed ~700MHz stall-clock). Latency/barrier/regalloc attacks all
//  failed (r1/r3 spilled at the 64-VGPR wall; r2 kept per-CU bytes equal).
//  Fixes:
//   - BR=32, 8 waves, grid 256 (1 block/CU): each wave = 1 n-slice x 2
//     M-tiles -> every 1KB B-frag feeds 4 MFMAs -> per-CU weight traffic
//     halves to 491KB/step.
//   - Weights stream via per-wave self-staged LDS rings (12 x 1KB/wave)
//     using global_load_lds (zero VGPR cost -> no spill failure mode) +
//     hand-counted s_waitcnt vmcnt(N). No cross-wave staging -> no new
//     barriers, no races. Ring prefetch issued during the pointwise phase.
//   - 2 waves/SIMD -> __launch_bounds__(512,2) frees 256 VGPRs.
//  Accumulation order per accumulator unchanged -> bit-identical output.
// K0 = 224: [u(86)|pad(10)|h1(128)] ; K1 = 256: [h1|h2]
#define K0T 7
#define K1T 8
#define KDT 4
#define NT0 32
#define NT1 32
#define NTD 5
#define S0  232   // A0 row stride (ushorts)
#define S1  264   // A1 row stride
#define BR  32
#define THR 512
#define RING 12   // per-wave B-frag ring depth (1KB slots)

// ws layout (bytes) — hi-only packed B fragments
#define B0P_OFF 0
#define B0P_SZ  (K0T * NT0 * 1024)       // 229376
#define B1P_OFF (B0P_OFF + B0P_SZ)
#define B1P_SZ  (K1T * NT1 * 1024)       // 262144
#define BDP_OFF (B1P_OFF + B1P_SZ)       // 491520
#define BDP_SZ  (KDT * NTD * 1024)       // 20480
#define B0P_N (B0P_SZ / 2)               // 114688
#define B1P_N (B1P_SZ / 2)               // 131072
#define TOT_N ((B0P_SZ + B1P_SZ + BDP_SZ) / 2)   // 256000

typedef __attribute__((ext_vector_type(8))) short bfrag;
typedef __attribute__((ext_vector_type(4))) float ffrag;

#define MFMA(AC, AA, BB) \
  AC = __builtin_amdgcn_mfma_f32_16x16x32_bf16((AA), (BB), (AC), 0, 0, 0)

template <int N> struct IC { static constexpr int value = N; };
template <int N, class F>
__device__ __forceinline__ void cfor(F&& f) {
  if constexpr (N > 0) {
    cfor<N - 1>(static_cast<F&&>(f));
    f(IC<N - 1>{});
  }
}

template <int N>
__device__ __forceinline__ void waitvm() {
  asm volatile("s_waitcnt vmcnt(%0)" :: "i"(N) : "memory");
  __builtin_amdgcn_sched_barrier(0);
}

__device__ __forceinline__ void gload_lds16(const void* g, void* l) {
  __builtin_amdgcn_global_load_lds(
      (const __attribute__((address_space(1))) unsigned int*)g,
      (__attribute__((address_space(3))) unsigned int*)l,
      16, 0, 0);
}

__device__ __forceinline__ unsigned short bf16rn(float f) {
  union { float f; unsigned int u; } cv; cv.f = f;
  unsigned int u = cv.u;
  u += 0x7FFFu + ((u >> 16) & 1u);   // round-to-nearest-even
  return (unsigned short)(u >> 16);
}
__device__ __forceinline__ float bf16tof(unsigned short h) {
  union { unsigned int u; float f; } cv; cv.u = ((unsigned int)h) << 16;
  return cv.f;
}
__device__ __forceinline__ float sigmoid_f(float v) {
  return __fdividef(1.f, 1.f + __expf(-v));
}
__device__ __forceinline__ float tanh_f(float v) {
  float av = fabsf(v);
  float e  = __expf(-2.f * av);
  float t  = __fdividef(1.f - e, 1.f + e);
  return copysignf(t, v);
}

// ---------------- prep: pack hi-only weights in MFMA fragment order ---------
__global__ void wm_prep(
    const float* __restrict__ Wih0, const float* __restrict__ Whh0,
    const float* __restrict__ Wih1, const float* __restrict__ Whh1,
    const float* __restrict__ Wd,
    unsigned short* __restrict__ wsu)
{
  const int idx = blockIdx.x * 256 + threadIdx.x;
  if (idx >= TOT_N) return;
  int region, l;
  if (idx < B0P_N)               { region = 0; l = idx; }
  else if (idx < B0P_N + B1P_N)  { region = 1; l = idx - B0P_N; }
  else                           { region = 2; l = idx - (B0P_N + B1P_N); }

  int k, nt, lane, j;
  if (region < 2) {
    k  = l >> 14;            // 32 tiles * 512 ushorts = 16384 per ktile
    int r1 = l & 16383;
    nt = r1 >> 9;
    int li = r1 & 511;
    lane = li >> 3; j = li & 7;
  } else {
    k  = l / 2560;           // 5 * 512 per ktile
    int r1 = l % 2560;
    nt = r1 >> 9;
    int li = r1 & 511;
    lane = li >> 3; j = li & 7;
  }
  const int n  = nt * 16 + (lane & 15);
  const int kk = k * 32 + (lane >> 4) * 8 + j;

  float v = 0.f;
  if (region == 0) {
    if (kk < IN_)                    v = Wih0[n * IN_ + kk];
    else if (kk >= 96 && kk < 224)   v = Whh0[n * H_ + (kk - 96)];
  } else if (region == 1) {
    v = (kk < H_) ? Wih1[n * H_ + kk] : Whh1[n * H_ + (kk - H_)];
  } else {
    if (n < OUT_)                    v = Wd[n * H_ + kk];
  }
  wsu[idx] = bf16rn(v);
}

// ---------------- main persistent-recurrence kernel --------------------------
// GEMM modes:
//  0: fused main (NF=60): j<32 -> B1 k=j>>2 ; else B0 k=(j-32)>>2
//  1: tail Ga full (NF=48): j<32 -> B1 ; else B0 k=3+((j-32)>>2)
//  2: tail Ga last (NF=32): B1 only
//  3: pose Gc (NF=12): B0 k=j>>2
//  4: init gemm0 (NF=28): B0 k=j>>2
__global__ __launch_bounds__(THR, 2) void wm_main(
    const float* __restrict__ x,
    const char*  __restrict__ wsb,
    const float* __restrict__ bih0, const float* __restrict__ bhh0,
    const float* __restrict__ bih1, const float* __restrict__ bhh1,
    const float* __restrict__ bd,
    float* __restrict__ out)
{
  __shared__ __align__(16) unsigned short A0h[BR * S0];
  __shared__ __align__(16) unsigned short A0l[BR * S0];
  __shared__ __align__(16) unsigned short A1h[BR * S1];
  __shared__ __align__(16) unsigned short A1l[BR * S1];
  __shared__ __align__(16) char RG[8][RING * 1024];   // per-wave B rings

  const int tid  = threadIdx.x;
  const int lane = tid & 63;
  const int uw   = tid >> 6;      // wave id = unit-slice id (0..7)
  const int ln15 = lane & 15;
  const int quad = lane >> 4;
  const int quad4 = quad * 4;
  const int lane16 = lane * 16;

  const char* B0 = wsb + B0P_OFF;
  const char* B1 = wsb + B1P_OFF;
  const char* BD = wsb + BDP_OFF;
  char* myring = &RG[uw][0];

  // zero LDS (h/c zero-init; A0 pads [86,96) and [224,232) stay zero)
  for (int i = tid; i < BR * S0; i += THR) { A0h[i] = 0; A0l[i] = 0; }
  for (int i = tid; i < BR * S1; i += THR) { A1h[i] = 0; A1l[i] = 0; }

  // bias preload — this wave's unit col = uw*16 + ln15, per gate g
  float b0r[4], b1r[4];
  #pragma unroll
  for (int g = 0; g < 4; ++g) {
    const int n = g * 128 + uw * 16 + ln15;
    b0r[g] = bih0[n] + bhh0[n];
    b1r[g] = bih1[n] + bhh1[n];
  }
  const int od = uw * 16 + ln15;
  const float bdr = (uw < NTD && od < OUT_) ? bd[od] : 0.f;

  float c1[2][4], c2[2][4];
  #pragma unroll
  for (int m = 0; m < 2; ++m)
    #pragma unroll
    for (int r = 0; r < 4; ++r) { c1[m][r] = 0.f; c2[m][r] = 0.f; }

  // A-frag offsets for the two M-tiles this wave covers
  const int a0b0 = ln15 * S0 + quad * 8;
  const int a0b1 = (16 + ln15) * S0 + quad * 8;
  const int a1b0 = ln15 * S1 + quad * 8;
  const int a1b1 = (16 + ln15) * S1 + quad * 8;
  const int unit = uw * 16 + ln15;
  const int xr_row = tid >> 4;             // staging: 32 rows x 16 lanes
  const int xr_col = tid & 15;

  ffrag acc0[2][4], acc1[2][4];

  // ------ lambdas ------------------------------------------------------------
  auto binit0 = [&]() {
    #pragma unroll
    for (int m = 0; m < 2; ++m)
      #pragma unroll
      for (int g = 0; g < 4; ++g) acc0[m][g] = (ffrag){b0r[g], b0r[g], b0r[g], b0r[g]};
  };
  auto binit1 = [&]() {
    #pragma unroll
    for (int m = 0; m < 2; ++m)
      #pragma unroll
      for (int g = 0; g < 4; ++g) acc1[m][g] = (ffrag){b1r[g], b1r[g], b1r[g], b1r[g]};
  };
  auto pw_l1 = [&]() {    // h1 from acc0; writes A0[96+], A1[0+]
    #pragma unroll
    for (int m = 0; m < 2; ++m)
      #pragma unroll
      for (int rr = 0; rr < 4; ++rr) {
        const float ig = sigmoid_f(acc0[m][0][rr]);
        const float fg = sigmoid_f(acc0[m][1][rr]);
        const float gg = tanh_f(acc0[m][2][rr]);
        const float og = sigmoid_f(acc0[m][3][rr]);
        const float c  = fmaf(fg, c1[m][rr], ig * gg);
        c1[m][rr] = c;
        const float h  = og * tanh_f(c);
        const unsigned short hi = bf16rn(h);
        const unsigned short lo = bf16rn(h - bf16tof(hi));
        const int row = m * 16 + quad4 + rr;
        A0h[row * S0 + 96 + unit] = hi;  A0l[row * S0 + 96 + unit] = lo;
        A1h[row * S1 + unit]      = hi;  A1l[row * S1 + unit]      = lo;
      }
  };
  auto pw_l2 = [&]() {    // h2 from acc1; writes A1[128+]
    #pragma unroll
    for (int m = 0; m < 2; ++m)
      #pragma unroll
      for (int rr = 0; rr < 4; ++rr) {
        const float ig = sigmoid_f(acc1[m][0][rr]);
        const float fg = sigmoid_f(acc1[m][1][rr]);
        const float gg = tanh_f(acc1[m][2][rr]);
        const float og = sigmoid_f(acc1[m][3][rr]);
        const float c  = fmaf(fg, c2[m][rr], ig * gg);
        c2[m][rr] = c;
        const float h  = og * tanh_f(c);
        const unsigned short hi = bf16rn(h);
        const unsigned short lo = bf16rn(h - bf16tof(hi));
        const int row = m * 16 + quad4 + rr;
        A1h[row * S1 + 128 + unit] = hi;  A1l[row * S1 + 128 + unit] = lo;
      }
  };
  auto stage_write = [&](float v, int idx) {
    const unsigned short hi = bf16rn(v);
    A0h[idx] = hi;
    A0l[idx] = bf16rn(v - bf16tof(hi));
  };

  // staged-GEMM: consume per-wave ring with counted vmcnt; issue next frags.
  auto run_gemm = [&](auto mc) {
    constexpr int MODE = decltype(mc)::value;
    constexpr int NF = MODE == 0 ? 60 : MODE == 1 ? 48 : MODE == 2 ? 32 :
                       MODE == 3 ? 12 : 28;
    bfrag ah0, al0, ah1, al1;
    cfor<NF>([&](auto jc) {
      constexpr int j  = decltype(jc)::value;
      constexpr bool b1 = (MODE <= 2) && (j < 32);
      constexpr int jj = b1 ? j : (MODE <= 1 ? j - 32 : j);
      constexpr int k  = (MODE == 1 && !b1) ? 3 + (jj >> 2) : (jj >> 2);
      constexpr int g  = jj & 3;
      waitvm<((NF - 1 - j) < (RING - 1) ? (NF - 1 - j) : (RING - 1))>();
      if constexpr (g == 0) {
        if constexpr (b1) {
          ah0 = *(const bfrag*)(A1h + a1b0 + k * 32);
          al0 = *(const bfrag*)(A1l + a1b0 + k * 32);
          ah1 = *(const bfrag*)(A1h + a1b1 + k * 32);
          al1 = *(const bfrag*)(A1l + a1b1 + k * 32);
        } else {
          ah0 = *(const bfrag*)(A0h + a0b0 + k * 32);
          al0 = *(const bfrag*)(A0l + a0b0 + k * 32);
          ah1 = *(const bfrag*)(A0h + a0b1 + k * 32);
          al1 = *(const bfrag*)(A0l + a0b1 + k * 32);
        }
      }
      const bfrag bh = *(const bfrag*)(myring + (j % RING) * 1024 + lane16);
      if constexpr (b1) {
        MFMA(acc1[0][g], ah0, bh); MFMA(acc1[1][g], ah1, bh);
        MFMA(acc1[0][g], al0, bh); MFMA(acc1[1][g], al1, bh);
      } else {
        MFMA(acc0[0][g], ah0, bh); MFMA(acc0[1][g], ah1, bh);
        MFMA(acc0[0][g], al0, bh); MFMA(acc0[1][g], al1, bh);
      }
      if constexpr (j + RING < NF) {
        constexpr int i  = j + RING;
        constexpr bool i1 = (MODE <= 2) && (i < 32);
        constexpr int ii = i1 ? i : (MODE <= 1 ? i - 32 : i);
        constexpr int ik = (MODE == 1 && !i1) ? 3 + (ii >> 2) : (ii >> 2);
        constexpr int ig = ii & 3;
        gload_lds16((i1 ? B1 : B0) + (size_t)((ik * 32 + ig * 8 + uw) * 1024) + lane16,
                    myring + (i % RING) * 1024);
      }
    });
  };
  auto prefetch = [&](auto mc) {
    constexpr int MODE = decltype(mc)::value;
    constexpr int NF = MODE == 0 ? 60 : MODE == 1 ? 48 : MODE == 2 ? 32 :
                       MODE == 3 ? 12 : 28;
    constexpr int NP = NF < RING ? NF : RING;
    cfor<NP>([&](auto jc) {
      constexpr int j  = decltype(jc)::value;
      constexpr bool b1 = (MODE <= 2) && (j < 32);
      constexpr int jj = b1 ? j : (MODE <= 1 ? j - 32 : j);
      constexpr int k  = (MODE == 1 && !b1) ? 3 + (jj >> 2) : (jj >> 2);
      constexpr int g  = jj & 3;
      gload_lds16((b1 ? B1 : B0) + (size_t)((k * 32 + g * 8 + uw) * 1024) + lane16,
                  myring + j * 1024);
    });
  };

  __syncthreads();   // zero-fill visible before staging overwrites

  // ---- prologue: stage x(0), prefetch, compute acc0(0) ----------------------
  {
    const float* xr = x + ((size_t)(blockIdx.x * BR + xr_row) * T_ + 0) * IN_;
    float xv[6];
    #pragma unroll
    for (int m = 0; m < 6; ++m) {
      const int k = xr_col + m * 16;
      xv[m] = (k < IN_) ? xr[k] : 0.f;
    }
    #pragma unroll
    for (int m = 0; m < 6; ++m) {
      const int k = xr_col + m * 16;
      if (k < IN_) stage_write(xv[m], xr_row * S0 + k);
    }
  }
  prefetch(IC<4>{});
  __syncthreads();

  binit0();
  run_gemm(IC<4>{});
  __syncthreads();

  // ---- fused main loop: t = 0..49 (2 barriers per timestep) -----------------
  for (int t = 0; t < T_; ++t) {
    // W phase: x loads first (so their wait skips the prefetch), ring prefetch
    // issue (latency hides under pointwise), pointwise, LDS writes.
    float xv[6];
    const bool stg = (t < T_ - 1);         // t=49: u(50)=x(49), already staged
    if (stg) {
      const float* xr = x + ((size_t)(blockIdx.x * BR + xr_row) * T_ + (t + 1)) * IN_;
      #pragma unroll
      for (int m = 0; m < 6; ++m) {
        const int k = xr_col + m * 16;
        xv[m] = (k < IN_) ? xr[k] : 0.f;
      }
    }
    prefetch(IC<0>{});
    if (t > 0) pw_l2();                    // h2(t-1)
    pw_l1();                               // h1(t)
    if (stg) {
      #pragma unroll
      for (int m = 0; m < 6; ++m) {
        const int k = xr_col + m * 16;
        if (k < IN_) stage_write(xv[m], xr_row * S0 + k);
      }
    }
    __syncthreads();   // h1(t), h2(t-1), x(t+1) visible; prefetch landed

    // G phase: gates1(t) + gates0(t+1) — one fat staged phase, no barriers.
    binit1();
    binit0();
    run_gemm(IC<0>{});
    __syncthreads();   // all reads done before next W overwrites
  }

  // ---- tail: t = 50..64 (pose feedback breaks full fusion) ------------------
  for (int t = T_; t < T_ + NPOSE; ++t) {
    const bool more = (t < T_ + NPOSE - 1);
    // Wa: prefetch Ga (first 12 frags identical for modes 1/2), h1(t)
    prefetch(IC<2>{});
    if (t == T_) pw_l2();                  // h2(49)
    pw_l1();                               // h1(t)
    __syncthreads();

    // Ga: gates1(t) full + (if more) gates0(t+1) k-tiles 3..6
    binit1();
    if (more) { binit0(); run_gemm(IC<1>{}); }
    else      { run_gemm(IC<2>{}); }
    __syncthreads();

    // Wb: prefetch Gc, h2(t)
    if (more) prefetch(IC<3>{});
    pw_l2();
    __syncthreads();

    // Gb: dense head (waves with uw<5, both M-tiles)
    const int s = t - T_;
    if (uw < NTD) {
      ffrag d0 = (ffrag){bdr, bdr, bdr, bdr};
      ffrag d1 = (ffrag){bdr, bdr, bdr, bdr};
      #pragma unroll
      for (int k = 0; k < KDT; ++k) {
        const bfrag ah0 = *(const bfrag*)(A1h + a1b0 + 128 + k * 32);
        const bfrag al0 = *(const bfrag*)(A1l + a1b0 + 128 + k * 32);
        const bfrag ah1 = *(const bfrag*)(A1h + a1b1 + 128 + k * 32);
        const bfrag al1 = *(const bfrag*)(A1l + a1b1 + 128 + k * 32);
        const bfrag bh  = *(const bfrag*)(BD + (size_t)((k * NTD + uw) * 1024) + lane16);
        MFMA(d0, ah0, bh); MFMA(d1, ah1, bh);
        MFMA(d0, al0, bh); MFMA(d1, al1, bh);
      }
      if (od < OUT_) {
        #pragma unroll
        for (int m = 0; m < 2; ++m)
          #pragma unroll
          for (int rr = 0; rr < 4; ++rr) {
            const int row = m * 16 + quad4 + rr;
            const float v = m ? d1[rr] : d0[rr];
            out[((size_t)(blockIdx.x * BR + row) * NPOSE + s) * OUT_ + od] = v;
            if (s < NPOSE - 1) {
              const unsigned short hi = bf16rn(v);
              A0h[row * S0 + od] = hi;
              A0l[row * S0 + od] = bf16rn(v - bf16tof(hi));
            }
          }
      }
    }
    __syncthreads();   // pose visible; Gc prefetch drained

    // Gc: gates0(t+1) k-tiles 0..2 (pose|cond region); accumulates into acc0.
    if (more) run_gemm(IC<3>{});
  }
}

extern "C" void kernel_launch(void* const* d_in, const int* in_sizes, int n_in,
                              void* d_out, int out_size, void* d_ws, size_t ws_size,
                              hipStream_t stream)
{
  const float* x    = (const float*)d_in[0];
  const float* Wih0 = (const float*)d_in[1];
  const float* Whh0 = (const float*)d_in[2];
  const float* bih0 = (const float*)d_in[3];
  const float* bhh0 = (const float*)d_in[4];
  const float* Wih1 = (const float*)d_in[5];
  const float* Whh1 = (const float*)d_in[6];
  const float* bih1 = (const float*)d_in[7];
  const float* bhh1 = (const float*)d_in[8];
  const float* Wd   = (const float*)d_in[9];
  const float* bd   = (const float*)d_in[10];

  wm_prep<<<(TOT_N + 255) / 256, 256, 0, stream>>>(Wih0, Whh0, Wih1, Whh1, Wd,
                                                   (unsigned short*)d_ws);
  wm_main<<<B_ / BR, THR, 0, stream>>>(x, (const char*)d_ws,
                                       bih0, bhh0, bih1, bhh1, bd,
                                       (float*)d_out);
}